// Round 18
// baseline (1810.649 us; speedup 1.0000x reference)
//
#include <hip/hip_runtime.h>
#include <cstddef>

// ---------------- problem constants ----------------
#define BB 2
#define DD 256
#define NH 8
#define NL 4
#define NP 4
#define DFF 1024
#define NLAYERS 6
#define Q_TOT 21760
#define NTOK (BB * Q_TOT)   // 43520
#define MTILES (NTOK / 128) // 340
#define LTILES (NTOK / 64)  // 680

typedef unsigned short ushort_t;
typedef __attribute__((ext_vector_type(8))) short bh8;
typedef __attribute__((ext_vector_type(4))) float fx4;

__device__ __forceinline__ ushort_t f2b(float x) {
  union { float f; unsigned u; } v; v.f = x;
  unsigned r = v.u + 0x7FFF + ((v.u >> 16) & 1);
  return (ushort_t)(r >> 16);
}
__device__ __forceinline__ float b2f(ushort_t b) {
  union { unsigned u; float f; } v; v.u = ((unsigned)b) << 16; return v.f;
}
__device__ __forceinline__ float b2f_hi(unsigned w) {
  union { unsigned u; float f; } v; v.u = w & 0xFFFF0000u; return v.f;
}
__device__ __forceinline__ float b2f_lo(unsigned w) {
  union { unsigned u; float f; } v; v.u = w << 16; return v.f;
}

__device__ __forceinline__ void gload16(const void* g, void* l) {
  __builtin_amdgcn_global_load_lds(
      (const __attribute__((address_space(1))) unsigned int*)g,
      (__attribute__((address_space(3))) unsigned int*)l, 16, 0, 0);
}

// ---------------- init: flatten + transpose (B,D,H,W) -> (B,Q,D) ----------------
__global__ __launch_bounds__(256) void flatten_level(
    const float* __restrict__ src, const float* __restrict__ pos,
    const float* __restrict__ lemb, float* __restrict__ X,
    ushort_t* __restrict__ Xb, ushort_t* __restrict__ POSb,
    ushort_t* __restrict__ QBb, int HW, int start, int lvl) {
  __shared__ float ts[32][33];
  __shared__ float tp[32][33];
  int p0 = blockIdx.x * 32, d0 = blockIdx.y * 32, b = blockIdx.z;
  const float* sb = src + (size_t)b * DD * HW;
  const float* pb = pos + (size_t)b * DD * HW;
  int px = threadIdx.x;
#pragma unroll
  for (int i = 0; i < 4; ++i) {
    int dl = threadIdx.y + i * 8;
    ts[dl][px] = sb[(size_t)(d0 + dl) * HW + p0 + px];
    tp[dl][px] = pb[(size_t)(d0 + dl) * HW + p0 + px];
  }
  __syncthreads();
  int dx = threadIdx.x;
#pragma unroll
  for (int i = 0; i < 4; ++i) {
    int pl = threadIdx.y + i * 8;
    size_t row = (size_t)b * Q_TOT + start + p0 + pl;
    float s = ts[dx][pl];
    float p = tp[dx][pl] + lemb[lvl * DD + d0 + dx];
    X[row * DD + d0 + dx] = s;
    Xb[row * DD + d0 + dx] = f2b(s);
    POSb[row * DD + d0 + dx] = f2b(p);
    QBb[row * DD + d0 + dx] = f2b(s + p);
  }
}

// ---------------- weight transpose + bf16: W[K][N] -> WT[rowOff+N][K] ----------------
__global__ __launch_bounds__(256) void transpose_w(const float* __restrict__ W,
                                                   ushort_t* __restrict__ WT,
                                                   int K, int N, int outStride,
                                                   int rowOff) {
  __shared__ float t[32][33];
  int n0 = blockIdx.x * 32, k0 = blockIdx.y * 32, l = blockIdx.z;
  const float* in = W + (size_t)l * K * N;
  ushort_t* out = WT + (size_t)l * outStride;
#pragma unroll
  for (int i = 0; i < 4; ++i) {
    int k = threadIdx.y + i * 8;
    t[k][threadIdx.x] = in[(size_t)(k0 + k) * N + n0 + threadIdx.x];
  }
  __syncthreads();
#pragma unroll
  for (int i = 0; i < 4; ++i) {
    int nn = threadIdx.y + i * 8;
    out[(size_t)(rowOff + n0 + nn) * K + k0 + threadIdx.x] = f2b(t[threadIdx.x][nn]);
  }
}

// ---------------- weight transpose + fp8-e4m3 (scaled): W[K][N] -> WT[N][K] ----------
__global__ __launch_bounds__(256) void transpose_w_fp8(const float* __restrict__ W,
                                                       unsigned char* __restrict__ WT,
                                                       int K, int N, float scale) {
  __shared__ float t[32][33];
  int n0 = blockIdx.x * 32, k0 = blockIdx.y * 32, l = blockIdx.z;
  const float* in = W + (size_t)l * K * N;
  unsigned char* out = WT + (size_t)l * N * K;
#pragma unroll
  for (int i = 0; i < 4; ++i) {
    int k = threadIdx.y + i * 8;
    t[k][threadIdx.x] = in[(size_t)(k0 + k) * N + n0 + threadIdx.x];
  }
  __syncthreads();
#pragma unroll
  for (int i = 0; i < 4; ++i) {
    int nn = threadIdx.y + i * 8;
    float v = t[threadIdx.x][nn] * scale;
    int p = __builtin_amdgcn_cvt_pk_fp8_f32(v, 0.f, 0, false);
    out[(size_t)(n0 + nn) * K + k0 + threadIdx.x] = (unsigned char)(p & 0xFF);
  }
}

__global__ void pack_bias(const float* __restrict__ b_off,
                          const float* __restrict__ b_aw,
                          float* __restrict__ b_qa) {
  int l = blockIdx.x, i = threadIdx.x;
  b_qa[l * 384 + i] = (i < 256) ? b_off[l * 256 + i] : b_aw[l * 128 + i - 256];
}

// ---- MERGED bf16 MFMA GEMM: qa (N=384, blocks x<3) + v (N=256, x>=3), K=256 ----
__global__ __launch_bounds__(256) void gemm_qav(
    const ushort_t* __restrict__ Aq, const ushort_t* __restrict__ Btq,
    const float* __restrict__ biasq, ushort_t* __restrict__ Cq,
    const ushort_t* __restrict__ Av, const ushort_t* __restrict__ Btv,
    const float* __restrict__ biasv, ushort_t* __restrict__ Cv) {
  __shared__ ushort_t As[128 * 64];
  __shared__ ushort_t Bs[128 * 64];
  const int K = 256;
  int tid = threadIdx.x;
  int bx = blockIdx.x;
  const ushort_t* A;
  const ushort_t* Bt;
  const float* bias;
  ushort_t* C;
  int N, n0;
  if (bx < 3) {
    A = Aq; Bt = Btq; bias = biasq; C = Cq; N = 384; n0 = bx * 128;
  } else {
    A = Av; Bt = Btv; bias = biasv; C = Cv; N = 256; n0 = (bx - 3) * 128;
  }
  int m0 = blockIdx.y * 128;
  int wid = tid >> 6, lane = tid & 63;
  int wr = wid >> 1, wc = wid & 1;

  fx4 acc[4][4];
#pragma unroll
  for (int i = 0; i < 4; ++i)
#pragma unroll
    for (int j = 0; j < 4; ++j) acc[i][j] = fx4{0.f, 0.f, 0.f, 0.f};

  const ushort_t* ga = A + (size_t)(m0 + (tid >> 3)) * K + (tid & 7) * 8;
  const ushort_t* gb = Bt + (size_t)(n0 + (tid >> 3)) * K + (tid & 7) * 8;
  int ldsbase = wid * 1024;

#pragma unroll 1
  for (int k0 = 0; k0 < K; k0 += 64) {
#pragma unroll
    for (int it = 0; it < 4; ++it) {
      gload16(ga + (size_t)(it * 32) * K + k0, (char*)As + ldsbase + it * 4096);
      gload16(gb + (size_t)(it * 32) * K + k0, (char*)Bs + ldsbase + it * 4096);
    }
    __syncthreads();
#pragma unroll
    for (int kk = 0; kk < 2; ++kk) {
      bh8 af[4], bf[4];
      int cb = kk * 64 + (lane >> 4) * 16;
      int ra = wr * 64 + (lane & 15);
      int rb = wc * 64 + (lane & 15);
#pragma unroll
      for (int i = 0; i < 4; ++i)
        af[i] = *(const bh8*)((const char*)As + (ra + i * 16) * 128 + cb);
#pragma unroll
      for (int i = 0; i < 4; ++i)
        bf[i] = *(const bh8*)((const char*)Bs + (rb + i * 16) * 128 + cb);
#pragma unroll
      for (int i = 0; i < 4; ++i)
#pragma unroll
        for (int j = 0; j < 4; ++j)
          acc[i][j] = __builtin_amdgcn_mfma_f32_16x16x32_bf16(af[i], bf[j], acc[i][j], 0, 0, 0);
    }
    __syncthreads();
  }

  int crow = m0 + wr * 64 + (lane >> 4) * 4;
  int ccol = n0 + wc * 64 + (lane & 15);
#pragma unroll
  for (int j = 0; j < 4; ++j) {
    float bv = bias[ccol + j * 16];
#pragma unroll
    for (int i = 0; i < 4; ++i) {
#pragma unroll
      for (int r = 0; r < 4; ++r) {
        float v = acc[i][j][r] + bv;
        size_t idx = (size_t)(crow + i * 16 + r) * N + ccol + j * 16;
        C[idx] = f2b(v);
      }
    }
  }
}

// ---- bf16 MFMA GEMM (64x256, BK=32, dbuf) + bf16 residual + LN1; writes Xq8 too ----
__global__ __launch_bounds__(256) void gemm_ln(
    const ushort_t* __restrict__ A, const ushort_t* __restrict__ Bt,
    const float* __restrict__ bias, const float* __restrict__ gamma,
    const float* __restrict__ beta, ushort_t* __restrict__ Xbio,
    unsigned char* __restrict__ Xq8, int K) {
  __shared__ ushort_t As[2][64 * 32];
  __shared__ ushort_t Bs[2][256 * 32];
  __shared__ float red[2][2][64];
  int tid = threadIdx.x;
  int m0 = blockIdx.x * 64;
  int wid = tid >> 6, lane = tid & 63;
  int wr = wid >> 1, wc = wid & 1;  // wave: rows wr*32..+32, cols wc*128..+128

  fx4 acc[2][8];
#pragma unroll
  for (int i = 0; i < 2; ++i)
#pragma unroll
    for (int j = 0; j < 8; ++j) acc[i][j] = fx4{0.f, 0.f, 0.f, 0.f};

  int srow = tid >> 2;
  int sslot = (tid & 3) ^ ((tid >> 3) & 3);
  const ushort_t* ga = A + (size_t)(m0 + srow) * K + sslot * 8;
  const ushort_t* gb = Bt + (size_t)srow * K + sslot * 8;
  int ldsoff = wid * 1024;

  int cbyte = (((lane >> 4) ^ ((lane >> 1) & 3)) << 4);
  int ra = wr * 32 + (lane & 15);
  int rb = wc * 128 + (lane & 15);

  // prologue: stage tile 0
  gload16(ga, (char*)As[0] + ldsoff);
#pragma unroll
  for (int it = 0; it < 4; ++it)
    gload16(gb + (size_t)(it * 64) * K, (char*)Bs[0] + it * 4096 + ldsoff);
  __syncthreads();

  int nt = K >> 5;
  int cur = 0;
  for (int t = 0; t < nt; ++t) {
    if (t + 1 < nt) {
      int k1 = (t + 1) << 5;
      gload16(ga + k1, (char*)As[cur ^ 1] + ldsoff);
#pragma unroll
      for (int it = 0; it < 4; ++it)
        gload16(gb + (size_t)(it * 64) * K + k1, (char*)Bs[cur ^ 1] + it * 4096 + ldsoff);
    }
    bh8 af[2], bf[8];
#pragma unroll
    for (int i = 0; i < 2; ++i)
      af[i] = *(const bh8*)((const char*)As[cur] + (ra + i * 16) * 64 + cbyte);
#pragma unroll
    for (int j = 0; j < 8; ++j)
      bf[j] = *(const bh8*)((const char*)Bs[cur] + (rb + j * 16) * 64 + cbyte);
#pragma unroll
    for (int i = 0; i < 2; ++i)
#pragma unroll
      for (int j = 0; j < 8; ++j)
        acc[i][j] = __builtin_amdgcn_mfma_f32_16x16x32_bf16(af[i], bf[j], acc[i][j], 0, 0, 0);
    __syncthreads();
    cur ^= 1;
  }

  int lg = lane >> 4, lc = lane & 15;
  float bv[8], gv[8], bev[8];
#pragma unroll
  for (int j = 0; j < 8; ++j) {
    int col = wc * 128 + j * 16 + lc;
    bv[j] = bias[col];
    gv[j] = gamma[col];
    bev[j] = beta[col];
  }
  // pass 1: v = acc + bias + bf16 residual; per-row sum/sumsq
#pragma unroll
  for (int i = 0; i < 2; ++i) {
#pragma unroll
    for (int r = 0; r < 4; ++r) {
      int rloc = wr * 32 + i * 16 + lg * 4 + r;
      const ushort_t* xr = Xbio + (size_t)(m0 + rloc) * DD + wc * 128 + lc;
      float s = 0.f, s2 = 0.f;
#pragma unroll
      for (int j = 0; j < 8; ++j) {
        float v = acc[i][j][r] + bv[j] + b2f(xr[j * 16]);
        acc[i][j][r] = v;
        s += v;
        s2 += v * v;
      }
#pragma unroll
      for (int o = 1; o < 16; o <<= 1) {
        s += __shfl_xor(s, o);
        s2 += __shfl_xor(s2, o);
      }
      if (lc == 0) {
        red[wc][0][rloc] = s;
        red[wc][1][rloc] = s2;
      }
    }
  }
  __syncthreads();
  // pass 2: normalize + write bf16 x and fp8 x (for the fp8 FFN phase 1)
#pragma unroll
  for (int i = 0; i < 2; ++i) {
#pragma unroll
    for (int r = 0; r < 4; ++r) {
      int rloc = wr * 32 + i * 16 + lg * 4 + r;
      float s = red[0][0][rloc] + red[1][0][rloc];
      float s2 = red[0][1][rloc] + red[1][1][rloc];
      float mmean = s * (1.f / 256.f);
      float var = s2 * (1.f / 256.f) - mmean * mmean;
      float inv = rsqrtf(var + 1e-5f);
      size_t rowb = (size_t)(m0 + rloc) * DD + wc * 128 + lc;
#pragma unroll
      for (int j = 0; j < 8; ++j) {
        float y = (acc[i][j][r] - mmean) * inv * gv[j] + bev[j];
        Xbio[rowb + j * 16] = f2b(y);
        int p8 = __builtin_amdgcn_cvt_pk_fp8_f32(y, 0.f, 0, false);
        Xq8[rowb + j * 16] = (unsigned char)(p8 & 0xFF);
      }
    }
  }
}

// ---- FULLY-FUSED FFN: fp8 phase 1 (Xq8 x W1f8) + fp8 H + fp8 W2; no setprio ----
// launch_bounds(512,2): 128-VGPR cap, no spill. Phase-1 operand bytes halved
// vs r17 (bf16): W1 fp8 x16 (acc/16), X fp8 (unit scale). Epilogues/LN as r17.
template <int LAST>
__global__ __launch_bounds__(512, 2) void ffn_fused(
    const ushort_t* __restrict__ Xio, const unsigned char* __restrict__ Xq8,
    const unsigned char* __restrict__ W1f8,
    const float* __restrict__ b1v, const unsigned char* __restrict__ W2f8,
    const float* __restrict__ b2v, const float* __restrict__ gamma,
    const float* __restrict__ beta, const ushort_t* __restrict__ POSb,
    ushort_t* __restrict__ QBb, float* __restrict__ Xf) {
  extern __shared__ char lds[];  // 65536 B: H fp8; reused for LN reductions
  int tid = threadIdx.x;
  int w = tid >> 6, l = tid & 63;
  int l15 = l & 15, l4 = l >> 4;
  int m0 = blockIdx.x * 64;

  const unsigned char* xq = Xq8 + (size_t)m0 * 256;

  // ---- phase 1: H^T = (X @ W1)^T, fp8 x fp8, four 32-col sub-chunks
#pragma unroll 1
  for (int sc = 0; sc < 4; ++sc) {
    fx4 acc1[4][2];
#pragma unroll
    for (int i = 0; i < 4; ++i)
#pragma unroll
      for (int j = 0; j < 2; ++j) acc1[i][j] = fx4{0.f, 0.f, 0.f, 0.f};
#pragma unroll
    for (int kk = 0; kk < 8; ++kk) {
      long aX[4], bW[2];
#pragma unroll
      for (int i = 0; i < 4; ++i)
        aX[i] = *(const long*)(xq + (size_t)(l15 + 16 * i) * 256 + kk * 32 + l4 * 8);
#pragma unroll
      for (int j = 0; j < 2; ++j)
        bW[j] = *(const long*)(W1f8 + (size_t)(w * 128 + sc * 32 + j * 16 + l15) * 256 +
                               kk * 32 + l4 * 8);
#pragma unroll
      for (int i = 0; i < 4; ++i)
#pragma unroll
        for (int j = 0; j < 2; ++j)
          acc1[i][j] = __builtin_amdgcn_mfma_f32_16x16x32_fp8_fp8(bW[j], aX[i], acc1[i][j], 0, 0, 0);
    }
    // epilogue: h = relu(acc/16 + b1) -> fp8, one dword store per frag
#pragma unroll
    for (int j = 0; j < 2; ++j) {
      int n0 = w * 128 + sc * 32 + j * 16 + l4 * 4;
      float4 bb4 = *(const float4*)(b1v + n0);
      int slot = n0 >> 4;
      int inner = l4 * 4;  // 0,4,8,12
#pragma unroll
      for (int i = 0; i < 4; ++i) {
        int m = i * 16 + l15;
        float h0 = fmaxf(acc1[i][j][0] * 0.0625f + bb4.x, 0.f);
        float h1 = fmaxf(acc1[i][j][1] * 0.0625f + bb4.y, 0.f);
        float h2 = fmaxf(acc1[i][j][2] * 0.0625f + bb4.z, 0.f);
        float h3 = fmaxf(acc1[i][j][3] * 0.0625f + bb4.w, 0.f);
        int d = __builtin_amdgcn_cvt_pk_fp8_f32(h0, h1, 0, false);
        d = __builtin_amdgcn_cvt_pk_fp8_f32(h2, h3, d, true);
        *(int*)(lds + m * 1024 + ((slot ^ (m & 7)) << 4) + inner) = d;
      }
    }
  }
  __syncthreads();

  // ---- phase 2: Y = H @ W2 (fp8 x fp8); wave w owns out-cols [w*32, w*32+32)
  fx4 acc2[4][2];
#pragma unroll
  for (int i = 0; i < 4; ++i)
#pragma unroll
    for (int j = 0; j < 2; ++j) acc2[i][j] = fx4{0.f, 0.f, 0.f, 0.f};

#pragma unroll 4
  for (int kt = 0; kt < 32; ++kt) {
    long aL[4], bL[2];
#pragma unroll
    for (int i = 0; i < 4; ++i) {
      int m = i * 16 + l15;
      int slot = kt * 2 + (l4 >> 1);
      aL[i] = *(const long*)(lds + m * 1024 + ((slot ^ (m & 7)) << 4) + (l4 & 1) * 8);
    }
#pragma unroll
    for (int j = 0; j < 2; ++j)
      bL[j] = *(const long*)(W2f8 + (size_t)(w * 32 + j * 16 + l15) * 1024 + kt * 32 + l4 * 8);
#pragma unroll
    for (int i = 0; i < 4; ++i)
#pragma unroll
      for (int j = 0; j < 2; ++j)
        acc2[i][j] = __builtin_amdgcn_mfma_f32_16x16x32_fp8_fp8(aL[i], bL[j], acc2[i][j], 0, 0, 0);
  }
  __syncthreads();  // all H reads done; lds reused for LN reductions

  float* red = (float*)lds;            // [2][8][64] = 4 KB
  float* minv = (float*)(lds + 4096);  // [64][2]

  float gv[2], bev[2], bv2[2];
#pragma unroll
  for (int j = 0; j < 2; ++j) {
    int col = w * 32 + j * 16 + l15;
    gv[j] = gamma[col];
    bev[j] = beta[col];
    bv2[j] = b2v[col];
  }
  // pass 1: v = acc2/16 + b2 + bf16 residual; row partial sums (per wave)
#pragma unroll
  for (int i = 0; i < 4; ++i) {
#pragma unroll
    for (int r = 0; r < 4; ++r) {
      int m = l4 * 4 + r + 16 * i;
      float s = 0.f, s2 = 0.f;
#pragma unroll
      for (int j = 0; j < 2; ++j) {
        int col = w * 32 + j * 16 + l15;
        float v = acc2[i][j][r] * 0.0625f + bv2[j] + b2f(Xio[(size_t)(m0 + m) * 256 + col]);
        acc2[i][j][r] = v;
        s += v;
        s2 += v * v;
      }
#pragma unroll
      for (int o = 1; o < 16; o <<= 1) {
        s += __shfl_xor(s, o);
        s2 += __shfl_xor(s2, o);
      }
      if (l15 == 0) {
        red[w * 64 + m] = s;
        red[512 + w * 64 + m] = s2;
      }
    }
  }
  __syncthreads();
  if (tid < 64) {
    float s = 0.f, s2 = 0.f;
#pragma unroll
    for (int ww = 0; ww < 8; ++ww) {
      s += red[ww * 64 + tid];
      s2 += red[512 + ww * 64 + tid];
    }
    float mean = s * (1.f / 256.f);
    float var = s2 * (1.f / 256.f) - mean * mean;
    minv[tid * 2] = mean;
    minv[tid * 2 + 1] = rsqrtf(var + 1e-5f);
  }
  __syncthreads();
  // pass 2: normalize; write bf16 x (+ q for next layer, or f32 x if last)
  ushort_t* XbOut = (ushort_t*)Xio;  // in-place (block owns its rows)
#pragma unroll
  for (int i = 0; i < 4; ++i) {
#pragma unroll
    for (int r = 0; r < 4; ++r) {
      int m = l4 * 4 + r + 16 * i;
      float mean = minv[m * 2], inv = minv[m * 2 + 1];
      size_t rowb = (size_t)(m0 + m) * 256;
#pragma unroll
      for (int j = 0; j < 2; ++j) {
        int col = w * 32 + j * 16 + l15;
        float y = (acc2[i][j][r] - mean) * inv * gv[j] + bev[j];
        XbOut[rowb + col] = f2b(y);
        if (LAST) Xf[rowb + col] = y;
        else QBb[rowb + col] = f2b(y + b2f(POSb[rowb + col]));
      }
    }
  }
}

// ---------------- fused softmax + meta + gather sampler ----------------
__global__ __launch_bounds__(256) void sample_v4(const ushort_t* __restrict__ Vb,
                                                 const ushort_t* __restrict__ QA,
                                                 ushort_t* __restrict__ SAMPb) {
  int nb = NTOK / 2;
  int bid = blockIdx.x;
  int newb = (bid & 7) * (nb >> 3) + (bid >> 3);  // XCD-chunked swizzle
  int t = newb * 2 + (threadIdx.x >> 7);
  int h = (threadIdx.x >> 4) & 7;
  int p = threadIdx.x & 15;

  int b = (t >= Q_TOT) ? 1 : 0;
  int qi = t - b * Q_TOT;
  int lwq = (qi < 16384) ? 7 : (qi < 20480) ? 6 : (qi < 21504) ? 5 : 4;
  int stq = (qi < 16384) ? 0 : (qi < 20480) ? 16384 : (qi < 21504) ? 20480 : 21504;
  int wt = 1 << lwq;
  int pidx = qi - stq;
  int iy = pidx >> lwq, ix = pidx & (wt - 1);
  float refx = (ix + 0.5f) / (float)wt;
  float refy = (iy + 0.5f) / (float)wt;

  // softmax over the 16 points (one logit per lane)
  float lgt = b2f(QA[(size_t)t * 384 + 256 + h * 16 + p]);
  float mxv = lgt;
#pragma unroll
  for (int o = 1; o < 16; o <<= 1) mxv = fmaxf(mxv, __shfl_xor(mxv, o, 16));
  float e = __expf(lgt - mxv);
  float sum = e;
#pragma unroll
  for (int o = 1; o < 16; o <<= 1) sum += __shfl_xor(sum, o, 16);
  float a = e / sum;

  // bilinear meta for point p = (level l, point pt)
  int l = p >> 2, pt = p & 3;
  int wl = 128 >> l;
  int LSl = (l > 0 ? 16384 : 0) + (l > 1 ? 4096 : 0) + (l > 2 ? 1024 : 0);
  float fw = (float)wl;
  unsigned ow = *(const unsigned*)(QA + (size_t)t * 384 + h * 32 + l * 8 + pt * 2);
  float ox = b2f_lo(ow), oy = b2f_hi(ow);
  float Xc = refx * fw + ox - 0.5f;
  float Yc = refy * fw + oy - 0.5f;
  float xf = floorf(Xc), yf = floorf(Yc);
  float wx = Xc - xf, wy = Yc - yf;
  int x0 = (int)xf, y0 = (int)yf;
  int x1 = x0 + 1, y1 = y0 + 1;
  float ok_x0 = (x0 >= 0 && x0 < wl) ? 1.f : 0.f;
  float ok_x1 = (x1 >= 0 && x1 < wl) ? 1.f : 0.f;
  float ok_y0 = (y0 >= 0 && y0 < wl) ? 1.f : 0.f;
  float ok_y1 = (y1 >= 0 && y1 < wl) ? 1.f : 0.f;
  int xc0 = min(max(x0, 0), wl - 1), xc1 = min(max(x1, 0), wl - 1);
  int yc0 = min(max(y0, 0), wl - 1), yc1 = min(max(y1, 0), wl - 1);
  float w00 = (1.f - wx) * (1.f - wy) * a * ok_x0 * ok_y0;
  float w10 = wx * (1.f - wy) * a * ok_x1 * ok_y0;
  float w01 = (1.f - wx) * wy * a * ok_x0 * ok_y1;
  float w11 = wx * wy * a * ok_x1 * ok_y1;
  int metaBase = ((b * Q_TOT + LSl + yc0 * wl + xc0) << 8) + h * 32;
  int metaDxy = (int)(((unsigned)((xc1 - xc0) << 8)) |
                      (((unsigned)((yc1 - yc0) * wl) << 8) << 16));
  int metaZ = (int)(((unsigned)f2b(w00) << 16) | f2b(w10));
  int metaW = (int)(((unsigned)f2b(w01) << 16) | f2b(w11));

  int c2 = p * 2;  // this lane's channel pair within the head
  float acc0 = 0.f, acc1 = 0.f;
#pragma unroll
  for (int pp = 0; pp < 16; ++pp) {
    int m0v = __shfl(metaBase, pp, 16);
    int m1v = __shfl(metaDxy, pp, 16);
    int mzv = __shfl(metaZ, pp, 16);
    int mwv = __shfl(metaW, pp, 16);
    unsigned dxy = (unsigned)m1v;
    int base = m0v + c2;
    int dx = (int)(dxy & 0xffffu);
    int dy = (int)(dxy >> 16);
    unsigned v00 = *(const unsigned*)(Vb + base);
    unsigned v10 = *(const unsigned*)(Vb + base + dx);
    unsigned v01 = *(const unsigned*)(Vb + base + dy);
    unsigned v11 = *(const unsigned*)(Vb + base + dy + dx);
    unsigned wz = (unsigned)mzv, ww = (unsigned)mwv;
    float f00 = b2f_hi(wz), f10 = b2f_lo(wz);
    float f01 = b2f_hi(ww), f11 = b2f_lo(ww);
    acc0 = fmaf(f00, b2f_lo(v00), acc0);
    acc1 = fmaf(f00, b2f_hi(v00), acc1);
    acc0 = fmaf(f10, b2f_lo(v10), acc0);
    acc1 = fmaf(f10, b2f_hi(v10), acc1);
    acc0 = fmaf(f01, b2f_lo(v01), acc0);
    acc1 = fmaf(f01, b2f_hi(v01), acc1);
    acc0 = fmaf(f11, b2f_lo(v11), acc0);
    acc1 = fmaf(f11, b2f_hi(v11), acc1);
  }
  unsigned outw = (unsigned)f2b(acc0) | ((unsigned)f2b(acc1) << 16);
  *(unsigned*)(SAMPb + (size_t)t * 256 + h * 32 + c2) = outw;
}

// ---------------- tail: spatial_shapes + level_start_index (as f32) ----------------
__global__ void write_tail(float* __restrict__ t) {
  int i = threadIdx.x;
  float v = 0.f;
  switch (i) {
    case 0: v = 128.f; break;
    case 1: v = 128.f; break;
    case 2: v = 64.f; break;
    case 3: v = 64.f; break;
    case 4: v = 32.f; break;
    case 5: v = 32.f; break;
    case 6: v = 16.f; break;
    case 7: v = 16.f; break;
    case 8: v = 0.f; break;
    case 9: v = 16384.f; break;
    case 10: v = 20480.f; break;
    case 11: v = 21504.f; break;
    default: return;
  }
  t[i] = v;
}

// ---------------- launch ----------------
extern "C" void kernel_launch(void* const* d_in, const int* in_sizes, int n_in,
                              void* d_out, int out_size, void* d_ws, size_t ws_size,
                              hipStream_t stream) {
  const float* src[4] = {(const float*)d_in[0], (const float*)d_in[2],
                         (const float*)d_in[4], (const float*)d_in[6]};
  const float* pos[4] = {(const float*)d_in[1], (const float*)d_in[3],
                         (const float*)d_in[5], (const float*)d_in[7]};
  const float* lemb = (const float*)d_in[8];
  const float* W_off = (const float*)d_in[9];
  const float* b_off = (const float*)d_in[10];
  const float* W_aw = (const float*)d_in[11];
  const float* b_aw = (const float*)d_in[12];
  const float* W_v = (const float*)d_in[13];
  const float* b_v = (const float*)d_in[14];
  const float* W_out = (const float*)d_in[15];
  const float* b_out = (const float*)d_in[16];
  const float* g1 = (const float*)d_in[17];
  const float* be1 = (const float*)d_in[18];
  const float* W1 = (const float*)d_in[19];
  const float* b1 = (const float*)d_in[20];
  const float* W2 = (const float*)d_in[21];
  const float* b2 = (const float*)d_in[22];
  const float* g2 = (const float*)d_in[23];
  const float* be2 = (const float*)d_in[24];

  float* X = (float*)d_out;  // final f32 x lands here (last layer only)

  // ---- workspace layout ----
  char* w = (char*)d_ws;
  const size_t SZ_B = (size_t)NTOK * 256 * 2;
  ushort_t* POSb = (ushort_t*)w;  w += SZ_B;
  ushort_t* Xb = (ushort_t*)w;    w += SZ_B;
  ushort_t* QBb = (ushort_t*)w;   w += SZ_B;
  ushort_t* QAb = (ushort_t*)w;   w += (size_t)NTOK * 384 * 2;
  ushort_t* Vb = (ushort_t*)w;    w += SZ_B;
  ushort_t* SAMPb = (ushort_t*)w; w += SZ_B;
  unsigned char* Xq8 = (unsigned char*)w; w += (size_t)NTOK * 256;
  ushort_t* WT_qa = (ushort_t*)w;  w += (size_t)NLAYERS * 384 * 256 * 2;
  ushort_t* WT_v = (ushort_t*)w;   w += (size_t)NLAYERS * 256 * 256 * 2;
  ushort_t* WT_out = (ushort_t*)w; w += (size_t)NLAYERS * 256 * 256 * 2;
  unsigned char* WT_1f8 = (unsigned char*)w; w += (size_t)NLAYERS * 1024 * 256;
  unsigned char* WT_2f8 = (unsigned char*)w; w += (size_t)NLAYERS * 256 * 1024;
  float* b_qa = (float*)w;         w += (size_t)NLAYERS * 384 * 4;

  // allow 64 KB dynamic LDS for the fused FFN kernel (idempotent)
  hipFuncSetAttribute((const void*)ffn_fused<0>,
                      hipFuncAttributeMaxDynamicSharedMemorySize, 65536);
  hipFuncSetAttribute((const void*)ffn_fused<1>,
                      hipFuncAttributeMaxDynamicSharedMemorySize, 65536);

  // ---- weight prep ----
  transpose_w<<<dim3(8, 8, NLAYERS), dim3(32, 8), 0, stream>>>(W_off, WT_qa, 256, 256, 384 * 256, 0);
  transpose_w<<<dim3(4, 8, NLAYERS), dim3(32, 8), 0, stream>>>(W_aw, WT_qa, 256, 128, 384 * 256, 256);
  pack_bias<<<NLAYERS, 384, 0, stream>>>(b_off, b_aw, b_qa);
  transpose_w<<<dim3(8, 8, NLAYERS), dim3(32, 8), 0, stream>>>(W_v, WT_v, 256, 256, 256 * 256, 0);
  transpose_w<<<dim3(8, 8, NLAYERS), dim3(32, 8), 0, stream>>>(W_out, WT_out, 256, 256, 256 * 256, 0);
  transpose_w_fp8<<<dim3(32, 8, NLAYERS), dim3(32, 8), 0, stream>>>(W1, WT_1f8, 256, 1024, 16.f);
  transpose_w_fp8<<<dim3(8, 32, NLAYERS), dim3(32, 8), 0, stream>>>(W2, WT_2f8, 1024, 256, 16.f);

  static const int LWh[4] = {128, 64, 32, 16};
  static const int LSh[4] = {0, 16384, 20480, 21504};
  for (int l = 0; l < 4; ++l) {
    int hw = LWh[l] * LWh[l];
    dim3 g(hw / 32, DD / 32, BB);
    flatten_level<<<g, dim3(32, 8), 0, stream>>>(src[l], pos[l], lemb, X, Xb, POSb,
                                                 QBb, hw, LSh[l], l);
  }
  write_tail<<<1, 16, 0, stream>>>(X + (size_t)NTOK * DD);

  for (int l = 0; l < NLAYERS; ++l) {
    // merged offsets+logits (N=384, from q) and values (N=256, from x) GEMMs
    gemm_qav<<<dim3(5, MTILES), 256, 0, stream>>>(
        QBb, WT_qa + (size_t)l * 384 * 256, b_qa + l * 384, QAb,
        Xb, WT_v + (size_t)l * 256 * 256, b_v + l * 256, Vb);
    // fused softmax + meta + gather
    sample_v4<<<NTOK / 2, 256, 0, stream>>>(Vb, QAb, SAMPb);
    // out projection + bf16 residual + LN1 (in-place on Xb; also emits fp8 X)
    gemm_ln<<<LTILES, 256, 0, stream>>>(
        SAMPb, WT_out + (size_t)l * 256 * 256, b_out + l * 256,
        g1 + l * DD, be1 + l * DD, Xb, Xq8, 256);
    // fully-fused FFN + LN2 (+ q for next layer / final f32 x)
    if (l + 1 < NLAYERS) {
      ffn_fused<0><<<LTILES, 512, 65536, stream>>>(
          Xb, Xq8, WT_1f8 + (size_t)l * 1024 * 256, b1 + l * DFF,
          WT_2f8 + (size_t)l * 256 * 1024, b2 + l * 256,
          g2 + l * DD, be2 + l * DD, POSb, QBb, X);
    } else {
      ffn_fused<1><<<LTILES, 512, 65536, stream>>>(
          Xb, Xq8, WT_1f8 + (size_t)l * 1024 * 256, b1 + l * DFF,
          WT_2f8 + (size_t)l * 256 * 1024, b2 + l * 256,
          g2 + l * DD, be2 + l * DD, POSb, QBb, X);
    }
  }
}

// Round 19
// 1767.507 us; speedup vs baseline: 1.0244x; 1.0244x over previous
//
#include <hip/hip_runtime.h>
#include <cstddef>

// ---------------- problem constants ----------------
#define BB 2
#define DD 256
#define NH 8
#define NL 4
#define NP 4
#define DFF 1024
#define NLAYERS 6
#define Q_TOT 21760
#define NTOK (BB * Q_TOT)   // 43520
#define MTILES (NTOK / 128) // 340
#define LTILES (NTOK / 64)  // 680

typedef unsigned short ushort_t;
typedef __attribute__((ext_vector_type(8))) short bh8;
typedef __attribute__((ext_vector_type(4))) float fx4;

__device__ __forceinline__ ushort_t f2b(float x) {
  union { float f; unsigned u; } v; v.f = x;
  unsigned r = v.u + 0x7FFF + ((v.u >> 16) & 1);
  return (ushort_t)(r >> 16);
}
__device__ __forceinline__ float b2f(ushort_t b) {
  union { unsigned u; float f; } v; v.u = ((unsigned)b) << 16; return v.f;
}
__device__ __forceinline__ float b2f_hi(unsigned w) {
  union { unsigned u; float f; } v; v.u = w & 0xFFFF0000u; return v.f;
}
__device__ __forceinline__ float b2f_lo(unsigned w) {
  union { unsigned u; float f; } v; v.u = w << 16; return v.f;
}

__device__ __forceinline__ void gload16(const void* g, void* l) {
  __builtin_amdgcn_global_load_lds(
      (const __attribute__((address_space(1))) unsigned int*)g,
      (__attribute__((address_space(3))) unsigned int*)l, 16, 0, 0);
}

// ---------------- init: flatten + transpose (B,D,H,W) -> (B,Q,D) ----------------
__global__ __launch_bounds__(256) void flatten_level(
    const float* __restrict__ src, const float* __restrict__ pos,
    const float* __restrict__ lemb, float* __restrict__ X,
    ushort_t* __restrict__ Xb, ushort_t* __restrict__ POSb,
    ushort_t* __restrict__ QBb, int HW, int start, int lvl) {
  __shared__ float ts[32][33];
  __shared__ float tp[32][33];
  int p0 = blockIdx.x * 32, d0 = blockIdx.y * 32, b = blockIdx.z;
  const float* sb = src + (size_t)b * DD * HW;
  const float* pb = pos + (size_t)b * DD * HW;
  int px = threadIdx.x;
#pragma unroll
  for (int i = 0; i < 4; ++i) {
    int dl = threadIdx.y + i * 8;
    ts[dl][px] = sb[(size_t)(d0 + dl) * HW + p0 + px];
    tp[dl][px] = pb[(size_t)(d0 + dl) * HW + p0 + px];
  }
  __syncthreads();
  int dx = threadIdx.x;
#pragma unroll
  for (int i = 0; i < 4; ++i) {
    int pl = threadIdx.y + i * 8;
    size_t row = (size_t)b * Q_TOT + start + p0 + pl;
    float s = ts[dx][pl];
    float p = tp[dx][pl] + lemb[lvl * DD + d0 + dx];
    X[row * DD + d0 + dx] = s;
    Xb[row * DD + d0 + dx] = f2b(s);
    POSb[row * DD + d0 + dx] = f2b(p);
    QBb[row * DD + d0 + dx] = f2b(s + p);
  }
}

// ---------------- weight transpose + bf16: W[K][N] -> WT[rowOff+N][K] ----------------
__global__ __launch_bounds__(256) void transpose_w(const float* __restrict__ W,
                                                   ushort_t* __restrict__ WT,
                                                   int K, int N, int outStride,
                                                   int rowOff) {
  __shared__ float t[32][33];
  int n0 = blockIdx.x * 32, k0 = blockIdx.y * 32, l = blockIdx.z;
  const float* in = W + (size_t)l * K * N;
  ushort_t* out = WT + (size_t)l * outStride;
#pragma unroll
  for (int i = 0; i < 4; ++i) {
    int k = threadIdx.y + i * 8;
    t[k][threadIdx.x] = in[(size_t)(k0 + k) * N + n0 + threadIdx.x];
  }
  __syncthreads();
#pragma unroll
  for (int i = 0; i < 4; ++i) {
    int nn = threadIdx.y + i * 8;
    out[(size_t)(rowOff + n0 + nn) * K + k0 + threadIdx.x] = f2b(t[threadIdx.x][nn]);
  }
}

// ---------------- weight transpose + fp8-e4m3 (scaled): W[K][N] -> WT[N][K] ----------
__global__ __launch_bounds__(256) void transpose_w_fp8(const float* __restrict__ W,
                                                       unsigned char* __restrict__ WT,
                                                       int K, int N, float scale) {
  __shared__ float t[32][33];
  int n0 = blockIdx.x * 32, k0 = blockIdx.y * 32, l = blockIdx.z;
  const float* in = W + (size_t)l * K * N;
  unsigned char* out = WT + (size_t)l * N * K;
#pragma unroll
  for (int i = 0; i < 4; ++i) {
    int k = threadIdx.y + i * 8;
    t[k][threadIdx.x] = in[(size_t)(k0 + k) * N + n0 + threadIdx.x];
  }
  __syncthreads();
#pragma unroll
  for (int i = 0; i < 4; ++i) {
    int nn = threadIdx.y + i * 8;
    float v = t[threadIdx.x][nn] * scale;
    int p = __builtin_amdgcn_cvt_pk_fp8_f32(v, 0.f, 0, false);
    out[(size_t)(n0 + nn) * K + k0 + threadIdx.x] = (unsigned char)(p & 0xFF);
  }
}

__global__ void pack_bias(const float* __restrict__ b_off,
                          const float* __restrict__ b_aw,
                          float* __restrict__ b_qa) {
  int l = blockIdx.x, i = threadIdx.x;
  b_qa[l * 384 + i] = (i < 256) ? b_off[l * 256 + i] : b_aw[l * 128 + i - 256];
}

// ---- MERGED bf16 MFMA GEMM: qa (N=384, blocks x<3) + v (N=256, x>=3), K=256 ----
__global__ __launch_bounds__(256) void gemm_qav(
    const ushort_t* __restrict__ Aq, const ushort_t* __restrict__ Btq,
    const float* __restrict__ biasq, ushort_t* __restrict__ Cq,
    const ushort_t* __restrict__ Av, const ushort_t* __restrict__ Btv,
    const float* __restrict__ biasv, ushort_t* __restrict__ Cv) {
  __shared__ ushort_t As[128 * 64];
  __shared__ ushort_t Bs[128 * 64];
  const int K = 256;
  int tid = threadIdx.x;
  int bx = blockIdx.x;
  const ushort_t* A;
  const ushort_t* Bt;
  const float* bias;
  ushort_t* C;
  int N, n0;
  if (bx < 3) {
    A = Aq; Bt = Btq; bias = biasq; C = Cq; N = 384; n0 = bx * 128;
  } else {
    A = Av; Bt = Btv; bias = biasv; C = Cv; N = 256; n0 = (bx - 3) * 128;
  }
  int m0 = blockIdx.y * 128;
  int wid = tid >> 6, lane = tid & 63;
  int wr = wid >> 1, wc = wid & 1;

  fx4 acc[4][4];
#pragma unroll
  for (int i = 0; i < 4; ++i)
#pragma unroll
    for (int j = 0; j < 4; ++j) acc[i][j] = fx4{0.f, 0.f, 0.f, 0.f};

  const ushort_t* ga = A + (size_t)(m0 + (tid >> 3)) * K + (tid & 7) * 8;
  const ushort_t* gb = Bt + (size_t)(n0 + (tid >> 3)) * K + (tid & 7) * 8;
  int ldsbase = wid * 1024;

#pragma unroll 1
  for (int k0 = 0; k0 < K; k0 += 64) {
#pragma unroll
    for (int it = 0; it < 4; ++it) {
      gload16(ga + (size_t)(it * 32) * K + k0, (char*)As + ldsbase + it * 4096);
      gload16(gb + (size_t)(it * 32) * K + k0, (char*)Bs + ldsbase + it * 4096);
    }
    __syncthreads();
#pragma unroll
    for (int kk = 0; kk < 2; ++kk) {
      bh8 af[4], bf[4];
      int cb = kk * 64 + (lane >> 4) * 16;
      int ra = wr * 64 + (lane & 15);
      int rb = wc * 64 + (lane & 15);
#pragma unroll
      for (int i = 0; i < 4; ++i)
        af[i] = *(const bh8*)((const char*)As + (ra + i * 16) * 128 + cb);
#pragma unroll
      for (int i = 0; i < 4; ++i)
        bf[i] = *(const bh8*)((const char*)Bs + (rb + i * 16) * 128 + cb);
#pragma unroll
      for (int i = 0; i < 4; ++i)
#pragma unroll
        for (int j = 0; j < 4; ++j)
          acc[i][j] = __builtin_amdgcn_mfma_f32_16x16x32_bf16(af[i], bf[j], acc[i][j], 0, 0, 0);
    }
    __syncthreads();
  }

  int crow = m0 + wr * 64 + (lane >> 4) * 4;
  int ccol = n0 + wc * 64 + (lane & 15);
#pragma unroll
  for (int j = 0; j < 4; ++j) {
    float bv = bias[ccol + j * 16];
#pragma unroll
    for (int i = 0; i < 4; ++i) {
#pragma unroll
      for (int r = 0; r < 4; ++r) {
        float v = acc[i][j][r] + bv;
        size_t idx = (size_t)(crow + i * 16 + r) * N + ccol + j * 16;
        C[idx] = f2b(v);
      }
    }
  }
}

// ---- bf16 MFMA GEMM (64x256, BK=32, dbuf) + bf16 residual + LayerNorm (LN1) ----
__global__ __launch_bounds__(256) void gemm_ln(
    const ushort_t* __restrict__ A, const ushort_t* __restrict__ Bt,
    const float* __restrict__ bias, const float* __restrict__ gamma,
    const float* __restrict__ beta, ushort_t* __restrict__ Xbio, int K) {
  __shared__ ushort_t As[2][64 * 32];
  __shared__ ushort_t Bs[2][256 * 32];
  __shared__ float red[2][2][64];
  int tid = threadIdx.x;
  int m0 = blockIdx.x * 64;
  int wid = tid >> 6, lane = tid & 63;
  int wr = wid >> 1, wc = wid & 1;  // wave: rows wr*32..+32, cols wc*128..+128

  fx4 acc[2][8];
#pragma unroll
  for (int i = 0; i < 2; ++i)
#pragma unroll
    for (int j = 0; j < 8; ++j) acc[i][j] = fx4{0.f, 0.f, 0.f, 0.f};

  int srow = tid >> 2;
  int sslot = (tid & 3) ^ ((tid >> 3) & 3);
  const ushort_t* ga = A + (size_t)(m0 + srow) * K + sslot * 8;
  const ushort_t* gb = Bt + (size_t)srow * K + sslot * 8;
  int ldsoff = wid * 1024;

  int cbyte = (((lane >> 4) ^ ((lane >> 1) & 3)) << 4);
  int ra = wr * 32 + (lane & 15);
  int rb = wc * 128 + (lane & 15);

  // prologue: stage tile 0
  gload16(ga, (char*)As[0] + ldsoff);
#pragma unroll
  for (int it = 0; it < 4; ++it)
    gload16(gb + (size_t)(it * 64) * K, (char*)Bs[0] + it * 4096 + ldsoff);
  __syncthreads();

  int nt = K >> 5;
  int cur = 0;
  for (int t = 0; t < nt; ++t) {
    if (t + 1 < nt) {
      int k1 = (t + 1) << 5;
      gload16(ga + k1, (char*)As[cur ^ 1] + ldsoff);
#pragma unroll
      for (int it = 0; it < 4; ++it)
        gload16(gb + (size_t)(it * 64) * K + k1, (char*)Bs[cur ^ 1] + it * 4096 + ldsoff);
    }
    bh8 af[2], bf[8];
#pragma unroll
    for (int i = 0; i < 2; ++i)
      af[i] = *(const bh8*)((const char*)As[cur] + (ra + i * 16) * 64 + cbyte);
#pragma unroll
    for (int j = 0; j < 8; ++j)
      bf[j] = *(const bh8*)((const char*)Bs[cur] + (rb + j * 16) * 64 + cbyte);
#pragma unroll
    for (int i = 0; i < 2; ++i)
#pragma unroll
      for (int j = 0; j < 8; ++j)
        acc[i][j] = __builtin_amdgcn_mfma_f32_16x16x32_bf16(af[i], bf[j], acc[i][j], 0, 0, 0);
    __syncthreads();
    cur ^= 1;
  }

  int lg = lane >> 4, lc = lane & 15;
  float bv[8], gv[8], bev[8];
#pragma unroll
  for (int j = 0; j < 8; ++j) {
    int col = wc * 128 + j * 16 + lc;
    bv[j] = bias[col];
    gv[j] = gamma[col];
    bev[j] = beta[col];
  }
  // pass 1: v = acc + bias + bf16 residual; per-row sum/sumsq
#pragma unroll
  for (int i = 0; i < 2; ++i) {
#pragma unroll
    for (int r = 0; r < 4; ++r) {
      int rloc = wr * 32 + i * 16 + lg * 4 + r;
      const ushort_t* xr = Xbio + (size_t)(m0 + rloc) * DD + wc * 128 + lc;
      float s = 0.f, s2 = 0.f;
#pragma unroll
      for (int j = 0; j < 8; ++j) {
        float v = acc[i][j][r] + bv[j] + b2f(xr[j * 16]);
        acc[i][j][r] = v;
        s += v;
        s2 += v * v;
      }
#pragma unroll
      for (int o = 1; o < 16; o <<= 1) {
        s += __shfl_xor(s, o);
        s2 += __shfl_xor(s2, o);
      }
      if (lc == 0) {
        red[wc][0][rloc] = s;
        red[wc][1][rloc] = s2;
      }
    }
  }
  __syncthreads();
  // pass 2: normalize + write bf16 (in-place residual stream)
#pragma unroll
  for (int i = 0; i < 2; ++i) {
#pragma unroll
    for (int r = 0; r < 4; ++r) {
      int rloc = wr * 32 + i * 16 + lg * 4 + r;
      float s = red[0][0][rloc] + red[1][0][rloc];
      float s2 = red[0][1][rloc] + red[1][1][rloc];
      float mmean = s * (1.f / 256.f);
      float var = s2 * (1.f / 256.f) - mmean * mmean;
      float inv = rsqrtf(var + 1e-5f);
      size_t rowb = (size_t)(m0 + rloc) * DD + wc * 128 + lc;
#pragma unroll
      for (int j = 0; j < 8; ++j) {
        float y = (acc[i][j][r] - mmean) * inv * gv[j] + bev[j];
        Xbio[rowb + j * 16] = f2b(y);
      }
    }
  }
}

// ---- FULLY-FUSED FFN (fp8 H in LDS + fp8 W2, spill-free; NO setprio) ----
// launch_bounds(512,2): HIP 2nd arg = min BLOCKS/CU -> 128-VGPR cap, no spill
// (r15/r17: VGPR=104, 156 us).
template <int LAST>
__global__ __launch_bounds__(512, 2) void ffn_fused(
    const ushort_t* __restrict__ Xio, const ushort_t* __restrict__ W1t,
    const float* __restrict__ b1v, const unsigned char* __restrict__ W2f8,
    const float* __restrict__ b2v, const float* __restrict__ gamma,
    const float* __restrict__ beta, const ushort_t* __restrict__ POSb,
    ushort_t* __restrict__ QBb, float* __restrict__ Xf) {
  extern __shared__ char lds[];  // 65536 B: H fp8; reused for LN reductions
  int tid = threadIdx.x;
  int w = tid >> 6, l = tid & 63;
  int l15 = l & 15, l4 = l >> 4;
  int m0 = blockIdx.x * 64;

  const ushort_t* xb = Xio + (size_t)m0 * 256;

  // ---- phase 1: H^T = (X @ W1)^T in four sub-chunks of 32 N-cols each
#pragma unroll 1
  for (int sc = 0; sc < 4; ++sc) {
    fx4 acc1[4][2];
#pragma unroll
    for (int i = 0; i < 4; ++i)
#pragma unroll
      for (int j = 0; j < 2; ++j) acc1[i][j] = fx4{0.f, 0.f, 0.f, 0.f};
#pragma unroll
    for (int kk = 0; kk < 8; ++kk) {
      bh8 af[4], bf[2];
#pragma unroll
      for (int i = 0; i < 4; ++i)
        af[i] = *(const bh8*)(xb + (size_t)(l15 + 16 * i) * 256 + kk * 32 + l4 * 8);
#pragma unroll
      for (int j = 0; j < 2; ++j)
        bf[j] = *(const bh8*)(W1t + (size_t)(w * 128 + sc * 32 + j * 16 + l15) * 256 +
                              kk * 32 + l4 * 8);
#pragma unroll
      for (int i = 0; i < 4; ++i)
#pragma unroll
        for (int j = 0; j < 2; ++j)
          acc1[i][j] = __builtin_amdgcn_mfma_f32_16x16x32_bf16(bf[j], af[i], acc1[i][j], 0, 0, 0);
    }
    // epilogue: bias + relu -> fp8, one dword store per frag
#pragma unroll
    for (int j = 0; j < 2; ++j) {
      int n0 = w * 128 + sc * 32 + j * 16 + l4 * 4;
      float4 bb4 = *(const float4*)(b1v + n0);
      int slot = n0 >> 4;
      int inner = l4 * 4;  // 0,4,8,12
#pragma unroll
      for (int i = 0; i < 4; ++i) {
        int m = i * 16 + l15;
        float h0 = fmaxf(acc1[i][j][0] + bb4.x, 0.f);
        float h1 = fmaxf(acc1[i][j][1] + bb4.y, 0.f);
        float h2 = fmaxf(acc1[i][j][2] + bb4.z, 0.f);
        float h3 = fmaxf(acc1[i][j][3] + bb4.w, 0.f);
        int d = __builtin_amdgcn_cvt_pk_fp8_f32(h0, h1, 0, false);
        d = __builtin_amdgcn_cvt_pk_fp8_f32(h2, h3, d, true);
        *(int*)(lds + m * 1024 + ((slot ^ (m & 7)) << 4) + inner) = d;
      }
    }
  }
  __syncthreads();

  // ---- phase 2: Y = H @ W2 (fp8 x fp8); wave w owns out-cols [w*32, w*32+32)
  fx4 acc2[4][2];
#pragma unroll
  for (int i = 0; i < 4; ++i)
#pragma unroll
    for (int j = 0; j < 2; ++j) acc2[i][j] = fx4{0.f, 0.f, 0.f, 0.f};

#pragma unroll 4
  for (int kt = 0; kt < 32; ++kt) {
    long aL[4], bL[2];
#pragma unroll
    for (int i = 0; i < 4; ++i) {
      int m = i * 16 + l15;
      int slot = kt * 2 + (l4 >> 1);
      aL[i] = *(const long*)(lds + m * 1024 + ((slot ^ (m & 7)) << 4) + (l4 & 1) * 8);
    }
#pragma unroll
    for (int j = 0; j < 2; ++j)
      bL[j] = *(const long*)(W2f8 + (size_t)(w * 32 + j * 16 + l15) * 1024 + kt * 32 + l4 * 8);
#pragma unroll
    for (int i = 0; i < 4; ++i)
#pragma unroll
      for (int j = 0; j < 2; ++j)
        acc2[i][j] = __builtin_amdgcn_mfma_f32_16x16x32_fp8_fp8(aL[i], bL[j], acc2[i][j], 0, 0, 0);
  }
  __syncthreads();  // all H reads done; lds reused for LN reductions

  float* red = (float*)lds;            // [2][8][64] = 4 KB
  float* minv = (float*)(lds + 4096);  // [64][2]

  float gv[2], bev[2], bv2[2];
#pragma unroll
  for (int j = 0; j < 2; ++j) {
    int col = w * 32 + j * 16 + l15;
    gv[j] = gamma[col];
    bev[j] = beta[col];
    bv2[j] = b2v[col];
  }
  // pass 1: v = acc2/16 + b2 + bf16 residual; row partial sums (per wave)
#pragma unroll
  for (int i = 0; i < 4; ++i) {
#pragma unroll
    for (int r = 0; r < 4; ++r) {
      int m = l4 * 4 + r + 16 * i;
      float s = 0.f, s2 = 0.f;
#pragma unroll
      for (int j = 0; j < 2; ++j) {
        int col = w * 32 + j * 16 + l15;
        float v = acc2[i][j][r] * 0.0625f + bv2[j] + b2f(Xio[(size_t)(m0 + m) * 256 + col]);
        acc2[i][j][r] = v;
        s += v;
        s2 += v * v;
      }
#pragma unroll
      for (int o = 1; o < 16; o <<= 1) {
        s += __shfl_xor(s, o);
        s2 += __shfl_xor(s2, o);
      }
      if (l15 == 0) {
        red[w * 64 + m] = s;
        red[512 + w * 64 + m] = s2;
      }
    }
  }
  __syncthreads();
  if (tid < 64) {
    float s = 0.f, s2 = 0.f;
#pragma unroll
    for (int ww = 0; ww < 8; ++ww) {
      s += red[ww * 64 + tid];
      s2 += red[512 + ww * 64 + tid];
    }
    float mean = s * (1.f / 256.f);
    float var = s2 * (1.f / 256.f) - mean * mean;
    minv[tid * 2] = mean;
    minv[tid * 2 + 1] = rsqrtf(var + 1e-5f);
  }
  __syncthreads();
  // pass 2: normalize; write bf16 x (+ q for next layer, or f32 x if last)
  ushort_t* XbOut = (ushort_t*)Xio;  // in-place (block owns its rows)
#pragma unroll
  for (int i = 0; i < 4; ++i) {
#pragma unroll
    for (int r = 0; r < 4; ++r) {
      int m = l4 * 4 + r + 16 * i;
      float mean = minv[m * 2], inv = minv[m * 2 + 1];
      size_t rowb = (size_t)(m0 + m) * 256;
#pragma unroll
      for (int j = 0; j < 2; ++j) {
        int col = w * 32 + j * 16 + l15;
        float y = (acc2[i][j][r] - mean) * inv * gv[j] + bev[j];
        XbOut[rowb + col] = f2b(y);
        if (LAST) Xf[rowb + col] = y;
        else QBb[rowb + col] = f2b(y + b2f(POSb[rowb + col]));
      }
    }
  }
}

// ---------------- fused softmax + meta + gather sampler ----------------
__global__ __launch_bounds__(256) void sample_v4(const ushort_t* __restrict__ Vb,
                                                 const ushort_t* __restrict__ QA,
                                                 ushort_t* __restrict__ SAMPb) {
  int nb = NTOK / 2;
  int bid = blockIdx.x;
  int newb = (bid & 7) * (nb >> 3) + (bid >> 3);  // XCD-chunked swizzle
  int t = newb * 2 + (threadIdx.x >> 7);
  int h = (threadIdx.x >> 4) & 7;
  int p = threadIdx.x & 15;

  int b = (t >= Q_TOT) ? 1 : 0;
  int qi = t - b * Q_TOT;
  int lwq = (qi < 16384) ? 7 : (qi < 20480) ? 6 : (qi < 21504) ? 5 : 4;
  int stq = (qi < 16384) ? 0 : (qi < 20480) ? 16384 : (qi < 21504) ? 20480 : 21504;
  int wt = 1 << lwq;
  int pidx = qi - stq;
  int iy = pidx >> lwq, ix = pidx & (wt - 1);
  float refx = (ix + 0.5f) / (float)wt;
  float refy = (iy + 0.5f) / (float)wt;

  // softmax over the 16 points (one logit per lane)
  float lgt = b2f(QA[(size_t)t * 384 + 256 + h * 16 + p]);
  float mxv = lgt;
#pragma unroll
  for (int o = 1; o < 16; o <<= 1) mxv = fmaxf(mxv, __shfl_xor(mxv, o, 16));
  float e = __expf(lgt - mxv);
  float sum = e;
#pragma unroll
  for (int o = 1; o < 16; o <<= 1) sum += __shfl_xor(sum, o, 16);
  float a = e / sum;

  // bilinear meta for point p = (level l, point pt)
  int l = p >> 2, pt = p & 3;
  int wl = 128 >> l;
  int LSl = (l > 0 ? 16384 : 0) + (l > 1 ? 4096 : 0) + (l > 2 ? 1024 : 0);
  float fw = (float)wl;
  unsigned ow = *(const unsigned*)(QA + (size_t)t * 384 + h * 32 + l * 8 + pt * 2);
  float ox = b2f_lo(ow), oy = b2f_hi(ow);
  float Xc = refx * fw + ox - 0.5f;
  float Yc = refy * fw + oy - 0.5f;
  float xf = floorf(Xc), yf = floorf(Yc);
  float wx = Xc - xf, wy = Yc - yf;
  int x0 = (int)xf, y0 = (int)yf;
  int x1 = x0 + 1, y1 = y0 + 1;
  float ok_x0 = (x0 >= 0 && x0 < wl) ? 1.f : 0.f;
  float ok_x1 = (x1 >= 0 && x1 < wl) ? 1.f : 0.f;
  float ok_y0 = (y0 >= 0 && y0 < wl) ? 1.f : 0.f;
  float ok_y1 = (y1 >= 0 && y1 < wl) ? 1.f : 0.f;
  int xc0 = min(max(x0, 0), wl - 1), xc1 = min(max(x1, 0), wl - 1);
  int yc0 = min(max(y0, 0), wl - 1), yc1 = min(max(y1, 0), wl - 1);
  float w00 = (1.f - wx) * (1.f - wy) * a * ok_x0 * ok_y0;
  float w10 = wx * (1.f - wy) * a * ok_x1 * ok_y0;
  float w01 = (1.f - wx) * wy * a * ok_x0 * ok_y1;
  float w11 = wx * wy * a * ok_x1 * ok_y1;
  int metaBase = ((b * Q_TOT + LSl + yc0 * wl + xc0) << 8) + h * 32;
  int metaDxy = (int)(((unsigned)((xc1 - xc0) << 8)) |
                      (((unsigned)((yc1 - yc0) * wl) << 8) << 16));
  int metaZ = (int)(((unsigned)f2b(w00) << 16) | f2b(w10));
  int metaW = (int)(((unsigned)f2b(w01) << 16) | f2b(w11));

  int c2 = p * 2;  // this lane's channel pair within the head
  float acc0 = 0.f, acc1 = 0.f;
#pragma unroll
  for (int pp = 0; pp < 16; ++pp) {
    int m0v = __shfl(metaBase, pp, 16);
    int m1v = __shfl(metaDxy, pp, 16);
    int mzv = __shfl(metaZ, pp, 16);
    int mwv = __shfl(metaW, pp, 16);
    unsigned dxy = (unsigned)m1v;
    int base = m0v + c2;
    int dx = (int)(dxy & 0xffffu);
    int dy = (int)(dxy >> 16);
    unsigned v00 = *(const unsigned*)(Vb + base);
    unsigned v10 = *(const unsigned*)(Vb + base + dx);
    unsigned v01 = *(const unsigned*)(Vb + base + dy);
    unsigned v11 = *(const unsigned*)(Vb + base + dy + dx);
    unsigned wz = (unsigned)mzv, ww = (unsigned)mwv;
    float f00 = b2f_hi(wz), f10 = b2f_lo(wz);
    float f01 = b2f_hi(ww), f11 = b2f_lo(ww);
    acc0 = fmaf(f00, b2f_lo(v00), acc0);
    acc1 = fmaf(f00, b2f_hi(v00), acc1);
    acc0 = fmaf(f10, b2f_lo(v10), acc0);
    acc1 = fmaf(f10, b2f_hi(v10), acc1);
    acc0 = fmaf(f01, b2f_lo(v01), acc0);
    acc1 = fmaf(f01, b2f_hi(v01), acc1);
    acc0 = fmaf(f11, b2f_lo(v11), acc0);
    acc1 = fmaf(f11, b2f_hi(v11), acc1);
  }
  unsigned outw = (unsigned)f2b(acc0) | ((unsigned)f2b(acc1) << 16);
  *(unsigned*)(SAMPb + (size_t)t * 256 + h * 32 + c2) = outw;
}

// ---------------- tail: spatial_shapes + level_start_index (as f32) ----------------
__global__ void write_tail(float* __restrict__ t) {
  int i = threadIdx.x;
  float v = 0.f;
  switch (i) {
    case 0: v = 128.f; break;
    case 1: v = 128.f; break;
    case 2: v = 64.f; break;
    case 3: v = 64.f; break;
    case 4: v = 32.f; break;
    case 5: v = 32.f; break;
    case 6: v = 16.f; break;
    case 7: v = 16.f; break;
    case 8: v = 0.f; break;
    case 9: v = 16384.f; break;
    case 10: v = 20480.f; break;
    case 11: v = 21504.f; break;
    default: return;
  }
  t[i] = v;
}

// ---------------- launch ----------------
extern "C" void kernel_launch(void* const* d_in, const int* in_sizes, int n_in,
                              void* d_out, int out_size, void* d_ws, size_t ws_size,
                              hipStream_t stream) {
  const float* src[4] = {(const float*)d_in[0], (const float*)d_in[2],
                         (const float*)d_in[4], (const float*)d_in[6]};
  const float* pos[4] = {(const float*)d_in[1], (const float*)d_in[3],
                         (const float*)d_in[5], (const float*)d_in[7]};
  const float* lemb = (const float*)d_in[8];
  const float* W_off = (const float*)d_in[9];
  const float* b_off = (const float*)d_in[10];
  const float* W_aw = (const float*)d_in[11];
  const float* b_aw = (const float*)d_in[12];
  const float* W_v = (const float*)d_in[13];
  const float* b_v = (const float*)d_in[14];
  const float* W_out = (const float*)d_in[15];
  const float* b_out = (const float*)d_in[16];
  const float* g1 = (const float*)d_in[17];
  const float* be1 = (const float*)d_in[18];
  const float* W1 = (const float*)d_in[19];
  const float* b1 = (const float*)d_in[20];
  const float* W2 = (const float*)d_in[21];
  const float* b2 = (const float*)d_in[22];
  const float* g2 = (const float*)d_in[23];
  const float* be2 = (const float*)d_in[24];

  float* X = (float*)d_out;  // final f32 x lands here (last layer only)

  // ---- workspace layout ----
  char* w = (char*)d_ws;
  const size_t SZ_B = (size_t)NTOK * 256 * 2;
  ushort_t* POSb = (ushort_t*)w;  w += SZ_B;
  ushort_t* Xb = (ushort_t*)w;    w += SZ_B;
  ushort_t* QBb = (ushort_t*)w;   w += SZ_B;
  ushort_t* QAb = (ushort_t*)w;   w += (size_t)NTOK * 384 * 2;
  ushort_t* Vb = (ushort_t*)w;    w += SZ_B;
  ushort_t* SAMPb = (ushort_t*)w; w += SZ_B;
  ushort_t* WT_qa = (ushort_t*)w;  w += (size_t)NLAYERS * 384 * 256 * 2;
  ushort_t* WT_v = (ushort_t*)w;   w += (size_t)NLAYERS * 256 * 256 * 2;
  ushort_t* WT_out = (ushort_t*)w; w += (size_t)NLAYERS * 256 * 256 * 2;
  ushort_t* WT_1 = (ushort_t*)w;   w += (size_t)NLAYERS * 1024 * 256 * 2;
  unsigned char* WT_2f8 = (unsigned char*)w; w += (size_t)NLAYERS * 256 * 1024;
  float* b_qa = (float*)w;         w += (size_t)NLAYERS * 384 * 4;

  // allow 64 KB dynamic LDS for the fused FFN kernel (idempotent)
  hipFuncSetAttribute((const void*)ffn_fused<0>,
                      hipFuncAttributeMaxDynamicSharedMemorySize, 65536);
  hipFuncSetAttribute((const void*)ffn_fused<1>,
                      hipFuncAttributeMaxDynamicSharedMemorySize, 65536);

  // ---- weight prep ----
  transpose_w<<<dim3(8, 8, NLAYERS), dim3(32, 8), 0, stream>>>(W_off, WT_qa, 256, 256, 384 * 256, 0);
  transpose_w<<<dim3(4, 8, NLAYERS), dim3(32, 8), 0, stream>>>(W_aw, WT_qa, 256, 128, 384 * 256, 256);
  pack_bias<<<NLAYERS, 384, 0, stream>>>(b_off, b_aw, b_qa);
  transpose_w<<<dim3(8, 8, NLAYERS), dim3(32, 8), 0, stream>>>(W_v, WT_v, 256, 256, 256 * 256, 0);
  transpose_w<<<dim3(8, 8, NLAYERS), dim3(32, 8), 0, stream>>>(W_out, WT_out, 256, 256, 256 * 256, 0);
  transpose_w<<<dim3(32, 8, NLAYERS), dim3(32, 8), 0, stream>>>(W1, WT_1, 256, 1024, 1024 * 256, 0);
  transpose_w_fp8<<<dim3(8, 32, NLAYERS), dim3(32, 8), 0, stream>>>(W2, WT_2f8, 1024, 256, 16.f);

  static const int LWh[4] = {128, 64, 32, 16};
  static const int LSh[4] = {0, 16384, 20480, 21504};
  for (int l = 0; l < 4; ++l) {
    int hw = LWh[l] * LWh[l];
    dim3 g(hw / 32, DD / 32, BB);
    flatten_level<<<g, dim3(32, 8), 0, stream>>>(src[l], pos[l], lemb, X, Xb, POSb,
                                                 QBb, hw, LSh[l], l);
  }
  write_tail<<<1, 16, 0, stream>>>(X + (size_t)NTOK * DD);

  for (int l = 0; l < NLAYERS; ++l) {
    // merged offsets+logits (N=384, from q) and values (N=256, from x) GEMMs
    gemm_qav<<<dim3(5, MTILES), 256, 0, stream>>>(
        QBb, WT_qa + (size_t)l * 384 * 256, b_qa + l * 384, QAb,
        Xb, WT_v + (size_t)l * 256 * 256, b_v + l * 256, Vb);
    // fused softmax + meta + gather
    sample_v4<<<NTOK / 2, 256, 0, stream>>>(Vb, QAb, SAMPb);
    // out projection + bf16 residual + LN1 (in-place on Xb)
    gemm_ln<<<LTILES, 256, 0, stream>>>(
        SAMPb, WT_out + (size_t)l * 256 * 256, b_out + l * 256,
        g1 + l * DD, be1 + l * DD, Xb, 256);
    // fully-fused FFN + LN2 (+ q for next layer / final f32 x)
    if (l + 1 < NLAYERS) {
      ffn_fused<0><<<LTILES, 512, 65536, stream>>>(
          Xb, WT_1 + (size_t)l * 1024 * 256, b1 + l * DFF,
          WT_2f8 + (size_t)l * 256 * 1024, b2 + l * 256,
          g2 + l * DD, be2 + l * DD, POSb, QBb, X);
    } else {
      ffn_fused<1><<<LTILES, 512, 65536, stream>>>(
          Xb, WT_1 + (size_t)l * 1024 * 256, b1 + l * DFF,
          WT_2f8 + (size_t)l * 256 * 1024, b2 + l * 256,
          g2 + l * DD, be2 + l * DD, POSb, QBb, X);
    }
  }
}